// Round 24
// baseline (154.623 us; speedup 1.0000x reference)
//
#include <hip/hip_runtime.h>
#include <hip/hip_fp16.h>
#include <stdint.h>

#define BB  2
#define NN  100000
#define MM  16384
#define SS  3
#define EE  262144
#define CC  32
#define HH  64
#define TPB 256
#define WPB 4            // waves per block
#define WIN 256          // edges per window
#define NWIN 2           // windows per wave (6144 windows / 3072 wave slots)
#define NMB  (WIN / 64)  // megabatches per window = 4
#define ACCR 24          // accumulator rows per wave

typedef _Float16 f16;
typedef _Float16 f16x4 __attribute__((ext_vector_type(4)));
typedef _Float16 f16x8 __attribute__((ext_vector_type(8)));
typedef float    f32x4 __attribute__((ext_vector_type(4)));

// packed-f16 gelu: x*(1 - 1/(1+2^(K1*x+K3*x^3))) on 2 lanes at once.
__device__ __forceinline__ __half2 gelu2(__half2 x){
  const __half2 K1 = __float2half2_rn(2.30218762f);
  const __half2 K3 = __float2half2_rn(0.10294232f);
  const __half2 ONE = __float2half2_rn(1.0f);
  __half2 x2 = __hmul2(x, x);
  __half2 u  = __hmul2(x, __hfma2(K3, x2, K1));
  __half2 e  = h2exp2(u);
  __half2 r  = h2rcp(__hadd2(e, ONE));
  return __hsub2(x, __hmul2(x, r));
}

// ---- pack: f16 W1(+b1, K=8 pad), W2, W3, W_lift(+b_lift at k=4..7) ----
extern "C" __global__ void magno_pack(const float* __restrict__ W1, const float* __restrict__ b1,
                                      const float* __restrict__ W2, const float* __restrict__ W3,
                                      const float* __restrict__ W_lift, const float* __restrict__ b_lift,
                                      f16* __restrict__ W1p, f16* __restrict__ W2h,
                                      f16* __restrict__ W3h, f16* __restrict__ WLp){
  int i = blockIdx.x * blockDim.x + threadIdx.x;
  if (i < HH * HH) W2h[i] = (f16)W2[i];
  if (i < CC * HH) W3h[i] = (f16)W3[i];
  if (i < HH * 8){
    int j = i >> 3, k = i & 7;
    float v = (k < 4) ? W1[j * 4 + k] : (k == 4 ? b1[j] : 0.f);
    W1p[i] = (f16)v;
  }
  if (i < CC * 8){
    int c = i >> 3, k = i & 7;
    float v = (k == 4) ? b_lift[c] : (k >= 5 ? W_lift[c * 3 + (k - 5)] : 0.f);
    WLp[i] = (f16)v;
  }
}

// ---- boundary detect: start/end of each sorted-row segment (NO atomics) ----
extern "C" __global__ void magno_bnd(const int* __restrict__ row_idx,
                                     uint32_t* __restrict__ startA,
                                     uint32_t* __restrict__ endA){
  int e = blockIdx.x * blockDim.x + threadIdx.x;
  if (e >= BB * SS * EE) return;
  int bs = e / EE, le = e % EE;
  const int* rows = row_idx + (size_t)bs * EE;
  int r = rows[le];
  if (le == 0 || rows[le - 1] != r) startA[(size_t)bs * MM + r] = (uint32_t)le;
  if (le == EE - 1 || rows[le + 1] != r) endA[(size_t)bs * MM + r] = (uint32_t)(le + 1);
}

// ---- coef2: one thread per latent node m; scale-MLP once, write all 6 (b,s) ----
extern "C" __global__ void magno_coef2(const float* __restrict__ lat,
                                       const uint32_t* __restrict__ startA,
                                       const uint32_t* __restrict__ endA,
                                       const float* __restrict__ Ws1, const float* __restrict__ bs1,
                                       const float* __restrict__ Ws2, const float* __restrict__ bs2,
                                       float* __restrict__ coefw){
  int m = blockIdx.x * blockDim.x + threadIdx.x;
  if (m >= MM) return;
  float la = lat[m * 2 + 0], lb = lat[m * 2 + 1];
  float t[16];
  #pragma unroll
  for (int i = 0; i < 16; i++)
    t[i] = fmaxf(fmaf(la, Ws1[i * 2 + 0], fmaf(lb, Ws1[i * 2 + 1], bs1[i])), 0.f);
  float a0 = bs2[0], a1 = bs2[1], a2 = bs2[2];
  #pragma unroll
  for (int i = 0; i < 16; i++){
    a0 = fmaf(t[i], Ws2[i], a0); a1 = fmaf(t[i], Ws2[16 + i], a1); a2 = fmaf(t[i], Ws2[32 + i], a2);
  }
  float mx = fmaxf(a0, fmaxf(a1, a2));
  float e0 = __expf(a0 - mx), e1 = __expf(a1 - mx), e2 = __expf(a2 - mx);
  float inv = 1.f / (e0 + e1 + e2);
  float sw[3] = { e0 * inv, e1 * inv, e2 * inv };
  #pragma unroll
  for (int b = 0; b < BB; b++)
    #pragma unroll
    for (int s = 0; s < SS; s++){
      size_t idx = (size_t)(b * SS + s) * MM + m;
      float c = (float)(endA[idx] - startA[idx]);
      coefw[idx] = sw[s] / fmaxf(c, 1.f);
    }
}

extern "C" __global__ void __launch_bounds__(TPB, 3)
magno_main(const float* __restrict__ x_coord,
           const float* __restrict__ pndata,
           const float* __restrict__ lat,
           const int* __restrict__ nbr_idx,
           const int* __restrict__ row_idx,
           const float* __restrict__ b2,
           const float* __restrict__ b3,
           const f16* __restrict__ W1p,
           const f16* __restrict__ W2h,
           const f16* __restrict__ W3h,
           const f16* __restrict__ WLp,
           const float* __restrict__ coefw,
           float* __restrict__ out)
{
  __shared__ __align__(16) f16   hbuf[WPB][32 * 64];   // ONE 32-edge tile per wave    16KB
  __shared__ __align__(16) f16   tst [WPB][64 * 8];    // staged t-vectors              4KB
  __shared__ ushort rloc[WPB][2][64];                  // local row per edge (dbuf)     1KB
  __shared__ float  accs[WPB][ACCR * CC];              // per-wave accumulators        12KB
  __shared__ __align__(16) f16   w2lds[HH * HH];       // W2 frags (XOR-swizzled)       8KB
  __shared__ __align__(16) f16   w3lds[CC * HH];       // W3 frags (XOR-swizzled)       4KB
  __shared__ __align__(16) f16   w1c[HH * 8];          // W1 compact rows               1KB
  __shared__ __align__(16) f16   wlc[CC * 8];          // W_lift compact rows         0.5KB
  __shared__ __align__(16) float b2c[HH];              // b2 copy                    0.25KB
  // total 47872 B -> 3 blocks/CU at 3 waves/EU

  const int tid  = threadIdx.x;
  const int wv   = tid >> 6;
  const int lane = tid & 63;
  const int g    = lane >> 4;
  const int n    = lane & 15;
  const int wslot = blockIdx.x * WPB + wv;

  const f16x8 zf = {0,0,0,0,0,0,0,0};
  const f32x4 z4 = {0.f,0.f,0.f,0.f};

  // ---- stage W2/W3 into block LDS with XOR swizzle (col ^= (row&7)<<3, f16 units) ----
  for (int c = tid; c < 512; c += TPB){
    int row = c >> 3, cb = (c & 7) * 8;
    f16x8 v = *(const f16x8*)(W2h + row * HH + cb);
    *(f16x8*)(w2lds + row * HH + (cb ^ ((row & 7) << 3))) = v;
  }
  for (int c = tid; c < 256; c += TPB){
    int row = c >> 3, cb = (c & 7) * 8;
    f16x8 v = *(const f16x8*)(W3h + row * HH + cb);
    *(f16x8*)(w3lds + row * HH + (cb ^ ((row & 7) << 3))) = v;
  }
  if (tid < 64) *(f16x8*)(w1c + tid * 8) = *(const f16x8*)(W1p + tid * 8);
  if (tid < 32) *(f16x8*)(wlc + tid * 8) = *(const f16x8*)(WLp + tid * 8);
  if (tid < 64) b2c[tid] = b2[tid];

  // ---- bias C-operand for l3 (kept in regs; only 8) ----
  f32x4 cb3[2];
  #pragma unroll
  for (int ct = 0; ct < 2; ct++){
    float v = b3[16 * ct + n];
    cb3[ct] = (f32x4){ v, v, v, v };
  }

  __syncthreads();   // weights staged

  f16* hb = hbuf[wv];
  f16* ts = tst[wv];
  const int nsw = (n & 7) << 3;                        // XOR swizzle term (f16 units)

  for (int w = 0; w < NWIN; w++){
    const int wid = wslot * NWIN + w;
    const int b   = wid / (SS * (EE / WIN));
    const int rem = wid % (SS * (EE / WIN));
    const int s   = rem / (EE / WIN);
    const int e0  = (rem % (EE / WIN)) * WIN;

    const int* rows = row_idx + (size_t)(b * SS + s) * EE;
    const int* nbrs = nbr_idx + (size_t)(b * SS + s) * EE;
    const int rowbase = rows[e0];
    const size_t cofs    = (size_t)(b * SS + s) * MM + rowbase;
    const size_t outbase = ((size_t)b * MM + rowbase) * CC;

    // ---- zero per-wave accumulator ----
    #pragma unroll
    for (int i = 0; i < ACCR * CC / 64; i++) accs[wv][i * 64 + lane] = 0.f;

    // ---- prologue: stage mega-batch 0 ----
    {
      int f0 = e0 + lane;
      int row = rows[f0], nbr = nbrs[f0];
      float2 la = *(const float2*)(lat + row * 2);
      float2 xc = *(const float2*)(x_coord + ((size_t)b * NN + nbr) * 2);
      const float* pp = pndata + ((size_t)b * NN + nbr) * 3;
      float p0 = pp[0], p1 = pp[1], p2 = pp[2];
      f16x8 t8 = {(f16)xc.x, (f16)xc.y, (f16)la.x, (f16)la.y, (f16)1.0f, (f16)p0, (f16)p1, (f16)p2};
      *(f16x8*)(ts + lane * 8) = t8;
      rloc[wv][0][lane] = (ushort)(row - rowbase);
    }

    for (int mb = 0; mb < NMB; mb++){
      const int cur = mb & 1;
      // ---- rolling prefetch: next mega-batch's gathers into regs ----
      int row2 = 0; float2 la2 = {0.f,0.f}, xc2 = {0.f,0.f};
      float q0 = 0.f, q1 = 0.f, q2 = 0.f;
      const bool pf = (mb < NMB - 1);
      if (pf){
        int f2 = e0 + (mb + 1) * 64 + lane;
        row2 = rows[f2]; int nbr2 = nbrs[f2];
        la2 = *(const float2*)(lat + row2 * 2);
        xc2 = *(const float2*)(x_coord + ((size_t)b * NN + nbr2) * 2);
        const float* pp = pndata + ((size_t)b * NN + nbr2) * 3;
        q0 = pp[0]; q1 = pp[1]; q2 = pp[2];
      }

      // ---- two 32-edge tiles processed sequentially through the single hbuf ----
      #pragma unroll
      for (int p = 0; p < 2; p++){
        // t8 frags for this tile (A-frag for pv / B-frag for swapped l1)
        f16x8 a1[2];
        #pragma unroll
        for (int mt = 0; mt < 2; mt++){
          f16x8 v = *(const f16x8*)(ts + (32 * p + 16 * mt + n) * 8);
          a1[mt] = (g == 0) ? v : zf;
        }

        // after the LAST read of tst, stage the prefetched mega-batch
        if (pf && p == 1){
          f16x8 t8 = {(f16)xc2.x, (f16)xc2.y, (f16)la2.x, (f16)la2.y, (f16)1.0f, (f16)q0, (f16)q1, (f16)q2};
          *(f16x8*)(ts + lane * 8) = t8;
          rloc[wv][cur ^ 1][lane] = (ushort)(row2 - rowbase);
        }

        // ---- layer 1 (swapped: D[j][edge]; packed-f16 gelu -> b64 writes) ----
        #pragma unroll
        for (int jt = 0; jt < 4; jt++){
          f16x8 w1a = *(const f16x8*)(w1c + (16 * jt + n) * 8);
          w1a = (g == 0) ? w1a : zf;
          #pragma unroll
          for (int et = 0; et < 2; et++){
            f32x4 d = __builtin_amdgcn_mfma_f32_16x16x32_f16(w1a, a1[et], z4, 0, 0, 0);
            __half2 h01 = gelu2(__floats2half2_rn(d[0], d[1]));
            __half2 h23 = gelu2(__floats2half2_rn(d[2], d[3]));
            uint2 pkv = { __builtin_bit_cast(uint32_t, h01), __builtin_bit_cast(uint32_t, h23) };
            *(uint2*)(hb + (16 * et + n) * 64 + ((16 * jt + 4 * g) ^ nsw)) = pkv;
          }
        }

        // ---- layer 2 (swapped; W2 frags + b2 C-operand per-use from LDS) ----
        f16x8 hB[2][2];
        #pragma unroll
        for (int et = 0; et < 2; et++)
          #pragma unroll
          for (int kt = 0; kt < 2; kt++)
            hB[et][kt] = *(const f16x8*)(hb + (16 * et + n) * 64 + ((32 * kt + 8 * g) ^ nsw));
        #pragma unroll
        for (int jt = 0; jt < 4; jt++){
          f16x8 wA0 = *(const f16x8*)(w2lds + (16 * jt + n) * HH + ((      8 * g) ^ nsw));
          f16x8 wA1 = *(const f16x8*)(w2lds + (16 * jt + n) * HH + ((32 + 8 * g) ^ nsw));
          f32x4 c2 = *(const f32x4*)(b2c + 16 * jt + 4 * g);
          #pragma unroll
          for (int et = 0; et < 2; et++){
            f32x4 d = __builtin_amdgcn_mfma_f32_16x16x32_f16(wA0, hB[et][0], c2, 0, 0, 0);
            d = __builtin_amdgcn_mfma_f32_16x16x32_f16(wA1, hB[et][1], d, 0, 0, 0);
            __half2 h01 = gelu2(__floats2half2_rn(d[0], d[1]));
            __half2 h23 = gelu2(__floats2half2_rn(d[2], d[3]));
            uint2 pkv = { __builtin_bit_cast(uint32_t, h01), __builtin_bit_cast(uint32_t, h23) };
            *(uint2*)(hb + (16 * et + n) * 64 + ((16 * jt + 4 * g) ^ nsw)) = pkv;
          }
        }

        // ---- layer 3 (unswapped; W3/W_lift frags per-use from LDS) + pv + epilogue ----
        f16x8 wla0 = *(const f16x8*)(wlc + (     n) * 8);
        f16x8 wla1 = *(const f16x8*)(wlc + (16 + n) * 8);
        wla0 = (g == 0) ? wla0 : zf;
        wla1 = (g == 0) ? wla1 : zf;
        #pragma unroll
        for (int mt = 0; mt < 2; mt++){
          int rw = 16 * mt + n;
          f16x8 a3k0 = *(const f16x8*)(hb + rw * 64 + ((     8 * g) ^ nsw));
          f16x8 a3k1 = *(const f16x8*)(hb + rw * 64 + ((32 + 8 * g) ^ nsw));
          f16x8 w300 = *(const f16x8*)(w3lds + (     n) * HH + ((      8 * g) ^ nsw));
          f16x8 w310 = *(const f16x8*)(w3lds + (     n) * HH + ((32 + 8 * g) ^ nsw));
          f16x8 w301 = *(const f16x8*)(w3lds + (16 + n) * HH + ((      8 * g) ^ nsw));
          f16x8 w311 = *(const f16x8*)(w3lds + (16 + n) * HH + ((32 + 8 * g) ^ nsw));
          f32x4 d0 = __builtin_amdgcn_mfma_f32_16x16x32_f16(a3k0, w300, cb3[0], 0, 0, 0);
          d0 = __builtin_amdgcn_mfma_f32_16x16x32_f16(a3k1, w310, d0, 0, 0, 0);
          f32x4 d1 = __builtin_amdgcn_mfma_f32_16x16x32_f16(a3k0, w301, cb3[1], 0, 0, 0);
          d1 = __builtin_amdgcn_mfma_f32_16x16x32_f16(a3k1, w311, d1, 0, 0, 0);
          f32x4 pv0 = __builtin_amdgcn_mfma_f32_16x16x32_f16(a1[mt], wla0, z4, 0, 0, 0);
          f32x4 pv1 = __builtin_amdgcn_mfma_f32_16x16x32_f16(a1[mt], wla1, z4, 0, 0, 0);

          uint2 rr = *(const uint2*)&rloc[wv][cur][32 * p + 16 * mt + 4 * g];
          int rl[4] = { (int)(rr.x & 0xffff), (int)(rr.x >> 16),
                        (int)(rr.y & 0xffff), (int)(rr.y >> 16) };
          float c0[4], c1[4];
          #pragma unroll
          for (int r = 0; r < 4; r++){
            c0[r] = d0[r] * pv0[r];
            c1[r] = d1[r] * pv1[r];
          }

          auto emitf = [&](int rl_, float s0_, float s1_){
            if (rl_ < ACCR){
              unsafeAtomicAdd(&accs[wv][rl_ * CC + n], s0_);
              unsafeAtomicAdd(&accs[wv][rl_ * CC + 16 + n], s1_);
            } else {
              float cf = coefw[cofs + rl_];
              unsafeAtomicAdd(out + outbase + (size_t)rl_ * CC + n, s0_ * cf);
              unsafeAtomicAdd(out + outbase + (size_t)rl_ * CC + 16 + n, s1_ * cf);
            }
          };

          int crl = rl[0]; float s0 = c0[0], s1 = c1[0];
          #pragma unroll
          for (int r = 1; r < 4; r++){
            if (rl[r] == crl){ s0 += c0[r]; s1 += c1[r]; }
            else { emitf(crl, s0, s1); crl = rl[r]; s0 = c0[r]; s1 = c1[r]; }
          }
          emitf(crl, s0, s1);
        }
      }
    }

    // ---- flush wave accumulator (coef-weighted) ----
    const float* cfb = coefw + cofs;
    #pragma unroll
    for (int i = 0; i < ACCR * CC / 64; i++){
      int idx = i * 64 + lane;
      float v = accs[wv][idx];
      if (v != 0.f){
        int r = idx >> 5, ch = idx & 31;
        unsafeAtomicAdd(out + outbase + r * CC + ch, v * cfb[r]);
      }
    }
  }
}

extern "C" void kernel_launch(void* const* d_in, const int* in_sizes, int n_in,
                              void* d_out, int out_size, void* d_ws, size_t ws_size,
                              hipStream_t stream)
{
  const float* x_coord = (const float*)d_in[0];
  const float* pndata  = (const float*)d_in[1];
  const float* lat     = (const float*)d_in[2];
  const int*   nbr_idx = (const int*)d_in[3];
  const int*   row_idx = (const int*)d_in[4];
  const float* W_lift  = (const float*)d_in[5];
  const float* b_lift  = (const float*)d_in[6];
  const float* W1      = (const float*)d_in[7];
  const float* b1      = (const float*)d_in[8];
  const float* W2      = (const float*)d_in[9];
  const float* b2      = (const float*)d_in[10];
  const float* W3      = (const float*)d_in[11];
  const float* b3      = (const float*)d_in[12];
  const float* Ws1     = (const float*)d_in[13];
  const float* bs1     = (const float*)d_in[14];
  const float* Ws2     = (const float*)d_in[15];
  const float* bs2     = (const float*)d_in[16];
  float* out = (float*)d_out;

  // ws layout: W2h 8KB | W3h 4KB | W1p 1KB | WLp 0.5KB | pad | coef 384KB | start 384KB | end 384KB
  f16*      W2h    = (f16*)d_ws;
  f16*      W3h    = (f16*)((char*)d_ws + 8192);
  f16*      W1p    = (f16*)((char*)d_ws + 12288);
  f16*      WLp    = (f16*)((char*)d_ws + 13312);
  float*    coefw  = (float*)((char*)d_ws + 16384);
  uint32_t* startA = (uint32_t*)((char*)d_ws + 16384 + 1 * (size_t)BB * SS * MM * 4);
  uint32_t* endA   = (uint32_t*)((char*)d_ws + 16384 + 2 * (size_t)BB * SS * MM * 4);

  hipMemsetAsync(d_out, 0, (size_t)out_size * sizeof(float), stream);
  hipMemsetAsync(startA, 0, 2 * (size_t)BB * SS * MM * 4, stream);
  hipLaunchKernelGGL(magno_pack, dim3(16), dim3(256), 0, stream,
                     W1, b1, W2, W3, W_lift, b_lift, W1p, W2h, W3h, WLp);
  hipLaunchKernelGGL(magno_bnd, dim3(BB * SS * EE / 256), dim3(256), 0, stream,
                     row_idx, startA, endA);
  hipLaunchKernelGGL(magno_coef2, dim3(MM / 256), dim3(256), 0, stream,
                     lat, startA, endA, Ws1, bs1, Ws2, bs2, coefw);
  hipLaunchKernelGGL(magno_main, dim3(BB * SS * (EE / WIN) / WPB / NWIN), dim3(TPB), 0, stream,
                     x_coord, pndata, lat, nbr_idx, row_idx,
                     b2, b3, W1p, W2h, W3h, WLp, coefw, out);
}

// Round 25
// 151.088 us; speedup vs baseline: 1.0234x; 1.0234x over previous
//
#include <hip/hip_runtime.h>
#include <hip/hip_fp16.h>
#include <stdint.h>

#define BB  2
#define NN  100000
#define MM  16384
#define SS  3
#define EE  262144
#define CC  32
#define HH  64
#define TPB 256
#define WPB 4            // waves per block
#define WIN 128          // edges per window
#define NWIN 4           // windows per wave (12288 / (768*4))
#define ACCR 16          // accumulator rows per wave

typedef _Float16 f16;
typedef _Float16 f16x4 __attribute__((ext_vector_type(4)));
typedef _Float16 f16x8 __attribute__((ext_vector_type(8)));
typedef float    f32x4 __attribute__((ext_vector_type(4)));

// packed-f16 gelu: x*(1 - 1/(1+2^(K1*x+K3*x^3))) on 2 lanes at once.
__device__ __forceinline__ __half2 gelu2(__half2 x){
  const __half2 K1 = __float2half2_rn(2.30218762f);
  const __half2 K3 = __float2half2_rn(0.10294232f);
  const __half2 ONE = __float2half2_rn(1.0f);
  __half2 x2 = __hmul2(x, x);
  __half2 u  = __hmul2(x, __hfma2(K3, x2, K1));
  __half2 e  = h2exp2(u);
  __half2 r  = h2rcp(__hadd2(e, ONE));
  return __hsub2(x, __hmul2(x, r));
}

// ---- pack: f16 W1(+b1, K=8 pad), W2, W3, W_lift(+b_lift at k=4..7) ----
extern "C" __global__ void magno_pack(const float* __restrict__ W1, const float* __restrict__ b1,
                                      const float* __restrict__ W2, const float* __restrict__ W3,
                                      const float* __restrict__ W_lift, const float* __restrict__ b_lift,
                                      f16* __restrict__ W1p, f16* __restrict__ W2h,
                                      f16* __restrict__ W3h, f16* __restrict__ WLp){
  int i = blockIdx.x * blockDim.x + threadIdx.x;
  if (i < HH * HH) W2h[i] = (f16)W2[i];
  if (i < CC * HH) W3h[i] = (f16)W3[i];
  if (i < HH * 8){
    int j = i >> 3, k = i & 7;
    float v = (k < 4) ? W1[j * 4 + k] : (k == 4 ? b1[j] : 0.f);
    W1p[i] = (f16)v;
  }
  if (i < CC * 8){
    int c = i >> 3, k = i & 7;
    float v = (k == 4) ? b_lift[c] : (k >= 5 ? W_lift[c * 3 + (k - 5)] : 0.f);
    WLp[i] = (f16)v;
  }
}

// ---- boundary detect: start/end of each sorted-row segment (NO atomics) ----
extern "C" __global__ void magno_bnd(const int* __restrict__ row_idx,
                                     uint32_t* __restrict__ startA,
                                     uint32_t* __restrict__ endA){
  int e = blockIdx.x * blockDim.x + threadIdx.x;
  if (e >= BB * SS * EE) return;
  int bs = e / EE, le = e % EE;
  const int* rows = row_idx + (size_t)bs * EE;
  int r = rows[le];
  if (le == 0 || rows[le - 1] != r) startA[(size_t)bs * MM + r] = (uint32_t)le;
  if (le == EE - 1 || rows[le + 1] != r) endA[(size_t)bs * MM + r] = (uint32_t)(le + 1);
}

// ---- coef2: one thread per latent node m; scale-MLP once, write all 6 (b,s) ----
extern "C" __global__ void magno_coef2(const float* __restrict__ lat,
                                       const uint32_t* __restrict__ startA,
                                       const uint32_t* __restrict__ endA,
                                       const float* __restrict__ Ws1, const float* __restrict__ bs1,
                                       const float* __restrict__ Ws2, const float* __restrict__ bs2,
                                       float* __restrict__ coefw){
  int m = blockIdx.x * blockDim.x + threadIdx.x;
  if (m >= MM) return;
  float la = lat[m * 2 + 0], lb = lat[m * 2 + 1];
  float t[16];
  #pragma unroll
  for (int i = 0; i < 16; i++)
    t[i] = fmaxf(fmaf(la, Ws1[i * 2 + 0], fmaf(lb, Ws1[i * 2 + 1], bs1[i])), 0.f);
  float a0 = bs2[0], a1 = bs2[1], a2 = bs2[2];
  #pragma unroll
  for (int i = 0; i < 16; i++){
    a0 = fmaf(t[i], Ws2[i], a0); a1 = fmaf(t[i], Ws2[16 + i], a1); a2 = fmaf(t[i], Ws2[32 + i], a2);
  }
  float mx = fmaxf(a0, fmaxf(a1, a2));
  float e0 = __expf(a0 - mx), e1 = __expf(a1 - mx), e2 = __expf(a2 - mx);
  float inv = 1.f / (e0 + e1 + e2);
  float sw[3] = { e0 * inv, e1 * inv, e2 * inv };
  #pragma unroll
  for (int b = 0; b < BB; b++)
    #pragma unroll
    for (int s = 0; s < SS; s++){
      size_t idx = (size_t)(b * SS + s) * MM + m;
      float c = (float)(endA[idx] - startA[idx]);
      coefw[idx] = sw[s] / fmaxf(c, 1.f);
    }
}

extern "C" __global__ void __launch_bounds__(TPB, 3)
magno_main(const float* __restrict__ x_coord,
           const float* __restrict__ pndata,
           const float* __restrict__ lat,
           const int* __restrict__ nbr_idx,
           const int* __restrict__ row_idx,
           const float* __restrict__ b2,
           const float* __restrict__ b3,
           const f16* __restrict__ W1p,
           const f16* __restrict__ W2h,
           const f16* __restrict__ W3h,
           const f16* __restrict__ WLp,
           const float* __restrict__ coefw,
           float* __restrict__ out)
{
  __shared__ __align__(16) f16   hbuf[WPB][32 * 64];   // ONE 32-edge tile per wave    16KB
  __shared__ __align__(16) f16   tst [WPB][64 * 8];    // staged t-vectors              4KB
  __shared__ ushort rloc[WPB][2][64];                  // local row per edge            1KB
  __shared__ float  accs[WPB][ACCR * CC];              // per-wave accumulators         8KB
  __shared__ __align__(16) f16   w2lds[HH * HH];       // W2 frags (XOR-swizzled)       8KB
  __shared__ __align__(16) f16   w3lds[CC * HH];       // W3 frags (XOR-swizzled)       4KB
  __shared__ __align__(16) f16   w1c[HH * 8];          // W1 compact rows               1KB
  __shared__ __align__(16) f16   wlc[CC * 8];          // W_lift compact rows         0.5KB
  __shared__ __align__(16) float b2c[HH];              // b2 copy                    0.25KB
  // total 44032 B -> 3 blocks/CU at 3 waves/EU

  const int tid  = threadIdx.x;
  const int wv   = tid >> 6;
  const int lane = tid & 63;
  const int g    = lane >> 4;
  const int n    = lane & 15;
  const int wslot = blockIdx.x * WPB + wv;

  const f16x8 zf = {0,0,0,0,0,0,0,0};
  const f32x4 z4 = {0.f,0.f,0.f,0.f};

  // ---- stage W2/W3 into block LDS with XOR swizzle (col ^= (row&7)<<3, f16 units) ----
  for (int c = tid; c < 512; c += TPB){
    int row = c >> 3, cb = (c & 7) * 8;
    f16x8 v = *(const f16x8*)(W2h + row * HH + cb);
    *(f16x8*)(w2lds + row * HH + (cb ^ ((row & 7) << 3))) = v;
  }
  for (int c = tid; c < 256; c += TPB){
    int row = c >> 3, cb = (c & 7) * 8;
    f16x8 v = *(const f16x8*)(W3h + row * HH + cb);
    *(f16x8*)(w3lds + row * HH + (cb ^ ((row & 7) << 3))) = v;
  }
  if (tid < 64) *(f16x8*)(w1c + tid * 8) = *(const f16x8*)(W1p + tid * 8);
  if (tid < 32) *(f16x8*)(wlc + tid * 8) = *(const f16x8*)(WLp + tid * 8);
  if (tid < 64) b2c[tid] = b2[tid];

  // ---- bias C-operand for l3 (kept in regs; only 8) ----
  f32x4 cb3[2];
  #pragma unroll
  for (int ct = 0; ct < 2; ct++){
    float v = b3[16 * ct + n];
    cb3[ct] = (f32x4){ v, v, v, v };
  }

  __syncthreads();   // weights staged

  f16* hb = hbuf[wv];
  f16* ts = tst[wv];
  const int nsw = (n & 7) << 3;                        // XOR swizzle term (f16 units)

  for (int w = 0; w < NWIN; w++){
    const int wid = wslot * NWIN + w;
    const int b   = wid / (SS * (EE / WIN));
    const int rem = wid % (SS * (EE / WIN));
    const int s   = rem / (EE / WIN);
    const int e0  = (rem % (EE / WIN)) * WIN;

    const int* rows = row_idx + (size_t)(b * SS + s) * EE;
    const int* nbrs = nbr_idx + (size_t)(b * SS + s) * EE;
    const int rowbase = rows[e0];
    const size_t cofs    = (size_t)(b * SS + s) * MM + rowbase;
    const size_t outbase = ((size_t)b * MM + rowbase) * CC;

    // ---- zero per-wave accumulator ----
    #pragma unroll
    for (int i = 0; i < ACCR * CC / 64; i++) accs[wv][i * 64 + lane] = 0.f;

    // ---- prologue: stage mega-batch 0 ----
    {
      int f0 = e0 + lane;
      int row = rows[f0], nbr = nbrs[f0];
      float2 la = *(const float2*)(lat + row * 2);
      float2 xc = *(const float2*)(x_coord + ((size_t)b * NN + nbr) * 2);
      const float* pp = pndata + ((size_t)b * NN + nbr) * 3;
      float p0 = pp[0], p1 = pp[1], p2 = pp[2];
      f16x8 t8 = {(f16)xc.x, (f16)xc.y, (f16)la.x, (f16)la.y, (f16)1.0f, (f16)p0, (f16)p1, (f16)p2};
      *(f16x8*)(ts + lane * 8) = t8;
      rloc[wv][0][lane] = (ushort)(row - rowbase);
    }

    #pragma unroll
    for (int mb = 0; mb < 2; mb++){
      // ---- prefetch next mega-batch's gathers ----
      int row2 = 0; float2 la2 = {0.f,0.f}, xc2 = {0.f,0.f};
      float q0 = 0.f, q1 = 0.f, q2 = 0.f;
      if (mb == 0){
        int f2 = e0 + 64 + lane;
        row2 = rows[f2]; int nbr2 = nbrs[f2];
        la2 = *(const float2*)(lat + row2 * 2);
        xc2 = *(const float2*)(x_coord + ((size_t)b * NN + nbr2) * 2);
        const float* pp = pndata + ((size_t)b * NN + nbr2) * 3;
        q0 = pp[0]; q1 = pp[1]; q2 = pp[2];
      }

      // ---- two 32-edge tiles processed sequentially through the single hbuf ----
      #pragma unroll
      for (int p = 0; p < 2; p++){
        // t8 frags for this tile (A-frag for pv / B-frag for swapped l1)
        f16x8 a1[2];
        #pragma unroll
        for (int mt = 0; mt < 2; mt++){
          f16x8 v = *(const f16x8*)(ts + (32 * p + 16 * mt + n) * 8);
          a1[mt] = (g == 0) ? v : zf;
        }

        // after the LAST read of tst, stage the prefetched mega-batch
        if (mb == 0 && p == 1){
          f16x8 t8 = {(f16)xc2.x, (f16)xc2.y, (f16)la2.x, (f16)la2.y, (f16)1.0f, (f16)q0, (f16)q1, (f16)q2};
          *(f16x8*)(ts + lane * 8) = t8;
          rloc[wv][1][lane] = (ushort)(row2 - rowbase);
        }

        // ---- layer 1 (swapped: D[j][edge]; packed-f16 gelu -> b64 writes) ----
        #pragma unroll
        for (int jt = 0; jt < 4; jt++){
          f16x8 w1a = *(const f16x8*)(w1c + (16 * jt + n) * 8);
          w1a = (g == 0) ? w1a : zf;
          #pragma unroll
          for (int et = 0; et < 2; et++){
            f32x4 d = __builtin_amdgcn_mfma_f32_16x16x32_f16(w1a, a1[et], z4, 0, 0, 0);
            __half2 h01 = gelu2(__floats2half2_rn(d[0], d[1]));
            __half2 h23 = gelu2(__floats2half2_rn(d[2], d[3]));
            uint2 pkv = { __builtin_bit_cast(uint32_t, h01), __builtin_bit_cast(uint32_t, h23) };
            *(uint2*)(hb + (16 * et + n) * 64 + ((16 * jt + 4 * g) ^ nsw)) = pkv;
          }
        }

        // ---- layer 2 (swapped; W2 frags + b2 C-operand per-use from LDS) ----
        f16x8 hB[2][2];
        #pragma unroll
        for (int et = 0; et < 2; et++)
          #pragma unroll
          for (int kt = 0; kt < 2; kt++)
            hB[et][kt] = *(const f16x8*)(hb + (16 * et + n) * 64 + ((32 * kt + 8 * g) ^ nsw));
        #pragma unroll
        for (int jt = 0; jt < 4; jt++){
          f16x8 wA0 = *(const f16x8*)(w2lds + (16 * jt + n) * HH + ((      8 * g) ^ nsw));
          f16x8 wA1 = *(const f16x8*)(w2lds + (16 * jt + n) * HH + ((32 + 8 * g) ^ nsw));
          f32x4 c2 = *(const f32x4*)(b2c + 16 * jt + 4 * g);
          #pragma unroll
          for (int et = 0; et < 2; et++){
            f32x4 d = __builtin_amdgcn_mfma_f32_16x16x32_f16(wA0, hB[et][0], c2, 0, 0, 0);
            d = __builtin_amdgcn_mfma_f32_16x16x32_f16(wA1, hB[et][1], d, 0, 0, 0);
            __half2 h01 = gelu2(__floats2half2_rn(d[0], d[1]));
            __half2 h23 = gelu2(__floats2half2_rn(d[2], d[3]));
            uint2 pkv = { __builtin_bit_cast(uint32_t, h01), __builtin_bit_cast(uint32_t, h23) };
            *(uint2*)(hb + (16 * et + n) * 64 + ((16 * jt + 4 * g) ^ nsw)) = pkv;
          }
        }

        // ---- layer 3 (unswapped; W3/W_lift frags per-use from LDS) + pv + epilogue ----
        f16x8 wla0 = *(const f16x8*)(wlc + (     n) * 8);
        f16x8 wla1 = *(const f16x8*)(wlc + (16 + n) * 8);
        wla0 = (g == 0) ? wla0 : zf;
        wla1 = (g == 0) ? wla1 : zf;
        #pragma unroll
        for (int mt = 0; mt < 2; mt++){
          int rw = 16 * mt + n;
          f16x8 a3k0 = *(const f16x8*)(hb + rw * 64 + ((     8 * g) ^ nsw));
          f16x8 a3k1 = *(const f16x8*)(hb + rw * 64 + ((32 + 8 * g) ^ nsw));
          f16x8 w300 = *(const f16x8*)(w3lds + (     n) * HH + ((      8 * g) ^ nsw));
          f16x8 w310 = *(const f16x8*)(w3lds + (     n) * HH + ((32 + 8 * g) ^ nsw));
          f16x8 w301 = *(const f16x8*)(w3lds + (16 + n) * HH + ((      8 * g) ^ nsw));
          f16x8 w311 = *(const f16x8*)(w3lds + (16 + n) * HH + ((32 + 8 * g) ^ nsw));
          f32x4 d0 = __builtin_amdgcn_mfma_f32_16x16x32_f16(a3k0, w300, cb3[0], 0, 0, 0);
          d0 = __builtin_amdgcn_mfma_f32_16x16x32_f16(a3k1, w310, d0, 0, 0, 0);
          f32x4 d1 = __builtin_amdgcn_mfma_f32_16x16x32_f16(a3k0, w301, cb3[1], 0, 0, 0);
          d1 = __builtin_amdgcn_mfma_f32_16x16x32_f16(a3k1, w311, d1, 0, 0, 0);
          f32x4 pv0 = __builtin_amdgcn_mfma_f32_16x16x32_f16(a1[mt], wla0, z4, 0, 0, 0);
          f32x4 pv1 = __builtin_amdgcn_mfma_f32_16x16x32_f16(a1[mt], wla1, z4, 0, 0, 0);

          uint2 rr = *(const uint2*)&rloc[wv][mb][32 * p + 16 * mt + 4 * g];
          int rl[4] = { (int)(rr.x & 0xffff), (int)(rr.x >> 16),
                        (int)(rr.y & 0xffff), (int)(rr.y >> 16) };
          float c0[4], c1[4];
          #pragma unroll
          for (int r = 0; r < 4; r++){
            c0[r] = d0[r] * pv0[r];
            c1[r] = d1[r] * pv1[r];
          }

          auto emitf = [&](int rl_, float s0_, float s1_){
            if (rl_ < ACCR){
              unsafeAtomicAdd(&accs[wv][rl_ * CC + n], s0_);
              unsafeAtomicAdd(&accs[wv][rl_ * CC + 16 + n], s1_);
            } else {
              float cf = coefw[cofs + rl_];
              unsafeAtomicAdd(out + outbase + (size_t)rl_ * CC + n, s0_ * cf);
              unsafeAtomicAdd(out + outbase + (size_t)rl_ * CC + 16 + n, s1_ * cf);
            }
          };

          int crl = rl[0]; float s0 = c0[0], s1 = c1[0];
          #pragma unroll
          for (int r = 1; r < 4; r++){
            if (rl[r] == crl){ s0 += c0[r]; s1 += c1[r]; }
            else { emitf(crl, s0, s1); crl = rl[r]; s0 = c0[r]; s1 = c1[r]; }
          }
          emitf(crl, s0, s1);
        }
      }
    }

    // ---- flush wave accumulator (coef-weighted) ----
    const float* cfb = coefw + cofs;
    #pragma unroll
    for (int i = 0; i < ACCR * CC / 64; i++){
      int idx = i * 64 + lane;
      float v = accs[wv][idx];
      if (v != 0.f){
        int r = idx >> 5, ch = idx & 31;
        unsafeAtomicAdd(out + outbase + r * CC + ch, v * cfb[r]);
      }
    }
  }
}

extern "C" void kernel_launch(void* const* d_in, const int* in_sizes, int n_in,
                              void* d_out, int out_size, void* d_ws, size_t ws_size,
                              hipStream_t stream)
{
  const float* x_coord = (const float*)d_in[0];
  const float* pndata  = (const float*)d_in[1];
  const float* lat     = (const float*)d_in[2];
  const int*   nbr_idx = (const int*)d_in[3];
  const int*   row_idx = (const int*)d_in[4];
  const float* W_lift  = (const float*)d_in[5];
  const float* b_lift  = (const float*)d_in[6];
  const float* W1      = (const float*)d_in[7];
  const float* b1      = (const float*)d_in[8];
  const float* W2      = (const float*)d_in[9];
  const float* b2      = (const float*)d_in[10];
  const float* W3      = (const float*)d_in[11];
  const float* b3      = (const float*)d_in[12];
  const float* Ws1     = (const float*)d_in[13];
  const float* bs1     = (const float*)d_in[14];
  const float* Ws2     = (const float*)d_in[15];
  const float* bs2     = (const float*)d_in[16];
  float* out = (float*)d_out;

  // ws layout: W2h 8KB | W3h 4KB | W1p 1KB | WLp 0.5KB | pad | coef 384KB | start 384KB | end 384KB
  f16*      W2h    = (f16*)d_ws;
  f16*      W3h    = (f16*)((char*)d_ws + 8192);
  f16*      W1p    = (f16*)((char*)d_ws + 12288);
  f16*      WLp    = (f16*)((char*)d_ws + 13312);
  float*    coefw  = (float*)((char*)d_ws + 16384);
  uint32_t* startA = (uint32_t*)((char*)d_ws + 16384 + 1 * (size_t)BB * SS * MM * 4);
  uint32_t* endA   = (uint32_t*)((char*)d_ws + 16384 + 2 * (size_t)BB * SS * MM * 4);

  hipMemsetAsync(d_out, 0, (size_t)out_size * sizeof(float), stream);
  hipMemsetAsync(startA, 0, 2 * (size_t)BB * SS * MM * 4, stream);
  hipLaunchKernelGGL(magno_pack, dim3(16), dim3(256), 0, stream,
                     W1, b1, W2, W3, W_lift, b_lift, W1p, W2h, W3h, WLp);
  hipLaunchKernelGGL(magno_bnd, dim3(BB * SS * EE / 256), dim3(256), 0, stream,
                     row_idx, startA, endA);
  hipLaunchKernelGGL(magno_coef2, dim3(MM / 256), dim3(256), 0, stream,
                     lat, startA, endA, Ws1, bs1, Ws2, bs2, coefw);
  hipLaunchKernelGGL(magno_main, dim3(BB * SS * (EE / WIN) / WPB / NWIN), dim3(TPB), 0, stream,
                     x_coord, pndata, lat, nbr_idx, row_idx,
                     b2, b3, W1p, W2h, W3h, WLp, coefw, out);
}